// Round 6
// baseline (309.127 us; speedup 1.0000x reference)
//
#include <hip/hip_runtime.h>

#define AMAX_CLIP 216.0f

typedef float f32x4 __attribute__((ext_vector_type(4)));

// ------------------------------------------------- amax partials (no atomics)
__global__ void amax_partial(const float* __restrict__ a, const float* __restrict__ b,
                             float* __restrict__ partials, int n4each, int blocksPer) {
  int half = blockIdx.x >= blocksPer;
  const float4* src = (const float4*)(half ? b : a);
  int lb = blockIdx.x - half * blocksPer;
  int tid = lb * blockDim.x + threadIdx.x;
  int stride = blocksPer * blockDim.x;
  float m = 0.f;
  for (int i = tid; i < n4each; i += stride) {
    float4 v = src[i];
    m = fmaxf(m, fmaxf(fmaxf(fabsf(v.x), fabsf(v.y)), fmaxf(fabsf(v.z), fabsf(v.w))));
  }
#pragma unroll
  for (int off = 32; off >= 1; off >>= 1) m = fmaxf(m, __shfl_down(m, off));
  __shared__ float sm[4];
  if ((threadIdx.x & 63) == 0) sm[threadIdx.x >> 6] = m;
  __syncthreads();
  if (threadIdx.x == 0)
    partials[blockIdx.x] = fmaxf(fmaxf(sm[0], sm[1]), fmaxf(sm[2], sm[3]));
}

// --------------------------------------- final reduce -> scales[2] (1 block)
__global__ void amax_finalize(const float* __restrict__ partials,
                              float* __restrict__ scales, int nPer) {
  int half = threadIdx.x >> 7;
  int lt = threadIdx.x & 127;
  float m = 0.f;
  for (int i = lt; i < nPer; i += 128) m = fmaxf(m, partials[half * nPer + i]);
#pragma unroll
  for (int off = 32; off >= 1; off >>= 1) m = fmaxf(m, __shfl_down(m, off));
  __shared__ float sm[4];
  if ((threadIdx.x & 63) == 0) sm[threadIdx.x >> 6] = m;
  __syncthreads();
  if (threadIdx.x == 0)   scales[0] = AMAX_CLIP / fmaxf(sm[0], sm[1]);
  if (threadIdx.x == 128) scales[1] = AMAX_CLIP / fmaxf(sm[2], sm[3]);
}

// --------------------------- quantize A (row-major, k-interleaved mfma layout)
// 8B granule w = g*8 + h*4 + u  ->  stored slot w' = g*8 + u*2 + h
// (within each 128-elem k-group; 16B chunk c=g*4+u then = both mfma k-blocks)
__global__ void quant_rowmajor(const float* __restrict__ x, unsigned char* __restrict__ q,
                               const float* __restrict__ scale, int nchunks) {
  float s = *scale;
  int tid = blockIdx.x * blockDim.x + threadIdx.x;
  int stride = gridDim.x * blockDim.x;
  const float4* x4 = (const float4*)x;
  uint2* q8 = (uint2*)q;
  for (int i = tid; i < nchunks; i += stride) {
    float4 a = x4[2 * i], b = x4[2 * i + 1];
    int w0 = __builtin_amdgcn_cvt_pk_fp8_f32(a.x * s, a.y * s, 0, false);
    w0 = __builtin_amdgcn_cvt_pk_fp8_f32(a.z * s, a.w * s, w0, true);
    int w1 = __builtin_amdgcn_cvt_pk_fp8_f32(b.x * s, b.y * s, 0, false);
    w1 = __builtin_amdgcn_cvt_pk_fp8_f32(b.z * s, b.w * s, w1, true);
    int w = i & 15;
    int wp = (w & 8) | ((w & 3) << 1) | ((w >> 2) & 1);
    q8[(i & ~15) | wp] = make_uint2((unsigned)w0, (unsigned)w1);
  }
}

// ----------------- quantize + transpose B -> Bt[N][K], k-interleaved layout
__global__ void quant_transpose(const float* __restrict__ B, unsigned char* __restrict__ qt,
                                const float* __restrict__ scale, int N, int K) {
  __shared__ float tile[64][65];
  float s = *scale;
  int n0 = blockIdx.x * 64;
  int k0 = blockIdx.y * 64;
  int t = threadIdx.x;
#pragma unroll
  for (int i = 0; i < 4; ++i) {
    int idx = t + i * 256;
    int r = idx >> 4;
    int c = (idx & 15) << 2;
    float4 v = *(const float4*)&B[(size_t)(k0 + r) * N + n0 + c];
    tile[r][c + 0] = v.x; tile[r][c + 1] = v.y;
    tile[r][c + 2] = v.z; tile[r][c + 3] = v.w;
  }
  __syncthreads();
  int n = t >> 2;               // 0..63
  int ks = (t & 3) << 4;        // 0,16,32,48
  unsigned wv[4];
#pragma unroll
  for (int g = 0; g < 4; ++g) {
    float f0 = tile[ks + g * 4 + 0][n] * s;
    float f1 = tile[ks + g * 4 + 1][n] * s;
    float f2 = tile[ks + g * 4 + 2][n] * s;
    float f3 = tile[ks + g * 4 + 3][n] * s;
    int ww = __builtin_amdgcn_cvt_pk_fp8_f32(f0, f1, 0, false);
    ww = __builtin_amdgcn_cvt_pk_fp8_f32(f2, f3, ww, true);
    wv[g] = (unsigned)ww;
  }
  // output granule permutation (w even here: u in {0,2})
  int kk8 = (k0 + ks) >> 3;           // global 8B-granule index in row
  int kg = kk8 >> 4, w = kk8 & 15;
  int wp = (w & 8) | ((w & 3) << 1) | ((w >> 2) & 1);
  uint2* q8 = (uint2*)qt;
  size_t rowbase = (size_t)(n0 + n) * (K / 8);
  q8[rowbase + (kg << 4) + wp]     = make_uint2(wv[0], wv[1]);
  q8[rowbase + (kg << 4) + wp + 2] = make_uint2(wv[2], wv[3]);
}

// ------------------------------------------------------------------ GEMM --
__device__ __forceinline__ void gload_lds16(const void* g, void* l) {
  __builtin_amdgcn_global_load_lds(
      (const __attribute__((address_space(1))) unsigned int*)g,
      (__attribute__((address_space(3))) unsigned int*)l, 16, 0, 0);
}

#define BM 256
#define BN 256
#define BKB 128   // K bytes (=elems) per tile
#define NT 32     // 4096 / 128

__global__ __launch_bounds__(512, 2) void gemm_fp8_8ph(
    const unsigned char* __restrict__ A,   // M x K fp8, interleaved
    const unsigned char* __restrict__ Bt,  // N x K fp8, interleaved
    float* __restrict__ C,
    const float* __restrict__ scales) {
  __shared__ unsigned char lds[2][2][BM * BKB];  // [dbuf][A|B][256*128] = 128 KiB
  const int t = threadIdx.x;
  const int w = t >> 6, l = t & 63;
  const int u = l >> 4, lr = l & 15;
  const int wm = w >> 2, wn = w & 3;             // 2M x 4N waves
  const int brow = blockIdx.y * BM, bcol = blockIdx.x * BN;

  const int sr = t >> 3, sc = t & 7;             // staging row/chunk decode

  f32x4 acc[8][4];
#pragma unroll
  for (int mi = 0; mi < 8; ++mi)
#pragma unroll
    for (int ni = 0; ni < 4; ++ni) acc[mi][ni] = (f32x4){0.f, 0.f, 0.f, 0.f};

  const unsigned char* gA = A + (size_t)brow * 4096;
  const unsigned char* gB = Bt + (size_t)bcol * 4096;

  auto stage = [&](int buf, int kt) {
#pragma unroll
    for (int jr = 0; jr < 4; ++jr) {
      int r = jr * 64 + sr;
      int c = sc ^ (r & 7);                      // pre-swizzled global source
      gload_lds16(gA + (size_t)r * 4096 + kt * 128 + c * 16,
                  &lds[buf][0][jr * 8192 + t * 16]);
    }
#pragma unroll
    for (int jr = 0; jr < 4; ++jr) {
      int r = jr * 64 + sr;
      int c = sc ^ (r & 7);
      gload_lds16(gB + (size_t)r * 4096 + kt * 128 + c * 16,
                  &lds[buf][1][jr * 8192 + t * 16]);
    }
  };

  auto phase = [&](int buf, int g, int q) {
    const unsigned char* bA = &lds[buf][0][0];
    const unsigned char* bB = &lds[buf][1][0];
    int qm = q >> 1, qn = q & 1;
    uint4 av[4], bv[2];
#pragma unroll
    for (int i = 0; i < 4; ++i) {
      int r = wm * 128 + (qm * 4 + i) * 16 + lr;
      av[i] = *(const uint4*)(bA + r * 128 + (((g * 4 + u) ^ (r & 7)) << 4));
    }
#pragma unroll
    for (int i = 0; i < 2; ++i) {
      int r = wn * 64 + (qn * 2 + i) * 16 + lr;
      bv[i] = *(const uint4*)(bB + r * 128 + (((g * 4 + u) ^ (r & 7)) << 4));
    }
    __builtin_amdgcn_s_barrier();
    asm volatile("s_waitcnt lgkmcnt(0)" ::: "memory");
    __builtin_amdgcn_sched_barrier(0);
    __builtin_amdgcn_s_setprio(1);
#pragma unroll
    for (int i = 0; i < 4; ++i)
#pragma unroll
      for (int jj = 0; jj < 2; ++jj) {
        int mi = qm * 4 + i, ni = qn * 2 + jj;
        long alo = ((const long*)&av[i])[0], ahi = ((const long*)&av[i])[1];
        long blo = ((const long*)&bv[jj])[0], bhi = ((const long*)&bv[jj])[1];
        acc[mi][ni] = __builtin_amdgcn_mfma_f32_16x16x32_fp8_fp8(alo, blo, acc[mi][ni], 0, 0, 0);
        acc[mi][ni] = __builtin_amdgcn_mfma_f32_16x16x32_fp8_fp8(ahi, bhi, acc[mi][ni], 0, 0, 0);
      }
    __builtin_amdgcn_s_setprio(0);
    __builtin_amdgcn_s_barrier();
  };

  stage(0, 0);                                   // prologue: tile 0 -> buf 0
  for (int kt = 0; kt < NT - 1; ++kt) {
    int cur = kt & 1;
    stage(cur ^ 1, kt + 1);                      // issue prefetch (8 gloads)
    asm volatile("s_waitcnt vmcnt(8)" ::: "memory");  // oldest 8 = buf[cur] done
    __builtin_amdgcn_s_barrier();
#pragma unroll
    for (int p = 0; p < 8; ++p) phase(cur, p >> 2, p & 3);
  }
  asm volatile("s_waitcnt vmcnt(0)" ::: "memory");
  __builtin_amdgcn_s_barrier();
#pragma unroll
  for (int p = 0; p < 8; ++p) phase((NT - 1) & 1, p >> 2, p & 3);

  // dequant, reference fp32 op order: scale=216/amax; out *= (1/s1)*(1/s2)
  float s1 = scales[0], s2 = scales[1];
  float factor = (1.0f / s1) * (1.0f / s2);
  int ccol = bcol + wn * 64 + lr;
  int crow0 = brow + wm * 128 + u * 4;
#pragma unroll
  for (int mi = 0; mi < 8; ++mi)
#pragma unroll
    for (int ni = 0; ni < 4; ++ni)
#pragma unroll
      for (int rr = 0; rr < 4; ++rr)
        C[(size_t)(crow0 + mi * 16 + rr) * 4096 + ccol + ni * 16] =
            acc[mi][ni][rr] * factor;
}

// ---------------------------------------------------------------- launch --
extern "C" void kernel_launch(void* const* d_in, const int* in_sizes, int n_in,
                              void* d_out, int out_size, void* d_ws, size_t ws_size,
                              hipStream_t stream) {
  const float* in1 = (const float*)d_in[0];
  const float* in2 = (const float*)d_in[1];
  float* out = (float*)d_out;
  const int M = 4096, N = 4096, K = 4096;

  float* scales = (float*)d_ws;
  unsigned char* q1 = (unsigned char*)d_ws + 256;
  unsigned char* q2t = q1 + (size_t)M * K;
  float* partials = (float*)q1;   // overlay, dead before quant_rowmajor writes

  const int blocksPer = 1024;
  amax_partial<<<2 * blocksPer, 256, 0, stream>>>(in1, in2, partials, (M * K) >> 2, blocksPer);
  amax_finalize<<<1, 256, 0, stream>>>(partials, scales, blocksPer);
  quant_rowmajor<<<2048, 256, 0, stream>>>(in1, q1, scales + 0, (M * K) / 8);
  quant_transpose<<<dim3(N / 64, K / 64), 256, 0, stream>>>(in2, q2t, scales + 1, N, K);
  gemm_fp8_8ph<<<dim3(N / BN, M / BM), 512, 0, stream>>>(q1, q2t, out, scales);
}

// Round 8
// 295.100 us; speedup vs baseline: 1.0475x; 1.0475x over previous
//
#include <hip/hip_runtime.h>

#define AMAX_CLIP 216.0f
#define BM 128
#define BN 128
#define BK 128

typedef float f32x4 __attribute__((ext_vector_type(4)));

// ------------------------------------------------- amax partials (no atomics)
__global__ void amax_partial(const float* __restrict__ a, const float* __restrict__ b,
                             float* __restrict__ partials, int n4each, int blocksPer) {
  int half = blockIdx.x >= blocksPer;
  const float4* src = (const float4*)(half ? b : a);
  int lb = blockIdx.x - half * blocksPer;
  int tid = lb * blockDim.x + threadIdx.x;
  int stride = blocksPer * blockDim.x;
  float m = 0.f;
  for (int i = tid; i < n4each; i += stride) {
    float4 v = src[i];
    m = fmaxf(m, fmaxf(fmaxf(fabsf(v.x), fabsf(v.y)), fmaxf(fabsf(v.z), fabsf(v.w))));
  }
#pragma unroll
  for (int off = 32; off >= 1; off >>= 1) m = fmaxf(m, __shfl_down(m, off));
  __shared__ float sm[4];
  if ((threadIdx.x & 63) == 0) sm[threadIdx.x >> 6] = m;
  __syncthreads();
  if (threadIdx.x == 0)
    partials[blockIdx.x] = fmaxf(fmaxf(sm[0], sm[1]), fmaxf(sm[2], sm[3]));
}

// --------------------------------------- final reduce -> scales[2] (1 block)
__global__ void amax_finalize(const float* __restrict__ partials,
                              float* __restrict__ scales, int nPer) {
  int half = threadIdx.x >> 7;
  int lt = threadIdx.x & 127;
  float m = 0.f;
  for (int i = lt; i < nPer; i += 128) m = fmaxf(m, partials[half * nPer + i]);
#pragma unroll
  for (int off = 32; off >= 1; off >>= 1) m = fmaxf(m, __shfl_down(m, off));
  __shared__ float sm[4];
  if ((threadIdx.x & 63) == 0) sm[threadIdx.x >> 6] = m;
  __syncthreads();
  if (threadIdx.x == 0)   scales[0] = AMAX_CLIP / fmaxf(sm[0], sm[1]);
  if (threadIdx.x == 128) scales[1] = AMAX_CLIP / fmaxf(sm[2], sm[3]);
}

// --------------- fused quantize: blocks [0,ABLK) -> A row-major (linear k),
//                 blocks [ABLK, ABLK+4096) -> B quantize+transpose 64x64 tile
#define ABLK 2048
__global__ void quant_fused(const float* __restrict__ A, unsigned char* __restrict__ qa,
                            const float* __restrict__ B, unsigned char* __restrict__ qbt,
                            const float* __restrict__ scales, int n4A, int N, int K) {
  __shared__ float tile[64][65];
  int t = threadIdx.x;
  if (blockIdx.x < ABLK) {
    // ---- A: perfectly coalesced; lane reads 16B, writes 4B
    float s = scales[0];
    const float4* x4 = (const float4*)A;
    unsigned* q4 = (unsigned*)qa;
    int tid = blockIdx.x * blockDim.x + t;
    int stride = ABLK * blockDim.x;
    for (int i = tid; i < n4A; i += stride) {
      float4 v = x4[i];
      int w0 = __builtin_amdgcn_cvt_pk_fp8_f32(v.x * s, v.y * s, 0, false);
      w0 = __builtin_amdgcn_cvt_pk_fp8_f32(v.z * s, v.w * s, w0, true);
      q4[i] = (unsigned)w0;
    }
  } else {
    // ---- B: quantize + transpose (Bt[N][K], linear k)
    float s = scales[1];
    int bid = blockIdx.x - ABLK;
    int n0 = (bid & 63) * 64;        // N/64 = 64
    int k0 = (bid >> 6) * 64;
#pragma unroll
    for (int i = 0; i < 4; ++i) {
      int idx = t + i * 256;
      int r = idx >> 4;
      int c = (idx & 15) << 2;
      float4 v = *(const float4*)&B[(size_t)(k0 + r) * N + n0 + c];
      tile[r][c + 0] = v.x; tile[r][c + 1] = v.y;
      tile[r][c + 2] = v.z; tile[r][c + 3] = v.w;
    }
    __syncthreads();
    int n = t >> 2;
    int ks = (t & 3) << 4;
    unsigned wv[4];
#pragma unroll
    for (int g = 0; g < 4; ++g) {
      float f0 = tile[ks + g * 4 + 0][n] * s;
      float f1 = tile[ks + g * 4 + 1][n] * s;
      float f2 = tile[ks + g * 4 + 2][n] * s;
      float f3 = tile[ks + g * 4 + 3][n] * s;
      int ww = __builtin_amdgcn_cvt_pk_fp8_f32(f0, f1, 0, false);
      ww = __builtin_amdgcn_cvt_pk_fp8_f32(f2, f3, ww, true);
      wv[g] = (unsigned)ww;
    }
    *(uint4*)&qbt[(size_t)(n0 + n) * K + k0 + ks] = make_uint4(wv[0], wv[1], wv[2], wv[3]);
  }
}

// ------------------------------------------------------------------ GEMM --
// (R4 proven configuration: 128x128x128 tile, 4 waves, gload_lds + XOR swizzle)
__device__ __forceinline__ void gload_lds16(const void* g, void* l) {
  __builtin_amdgcn_global_load_lds(
      (const __attribute__((address_space(1))) unsigned int*)g,
      (__attribute__((address_space(3))) unsigned int*)l, 16, 0, 0);
}

__global__ __launch_bounds__(256) void gemm_fp8(
    const unsigned char* __restrict__ A,   // M x K fp8
    const unsigned char* __restrict__ Bt,  // N x K fp8
    float* __restrict__ C,                 // M x N fp32
    const float* __restrict__ scales, int M, int N, int K) {
  __shared__ unsigned char lA[BM * BK];
  __shared__ unsigned char lB[BN * BK];
  int t = threadIdx.x;
  int brow = blockIdx.y * BM;
  int bcol = blockIdx.x * BN;
  int w = t >> 6, l = t & 63;
  int wm = w >> 1, wn = w & 1;

  int r0 = t >> 3;   // staging row (+32 per i)
  int cs = t & 7;    // stored chunk

  f32x4 acc[4][4];
#pragma unroll
  for (int mi = 0; mi < 4; ++mi)
#pragma unroll
    for (int ni = 0; ni < 4; ++ni)
      acc[mi][ni] = (f32x4){0.f, 0.f, 0.f, 0.f};

  for (int kt = 0; kt < K; kt += BK) {
#pragma unroll
    for (int i = 0; i < 4; ++i) {
      int r = r0 + i * 32;
      int cl = cs ^ (r & 7);   // pre-swizzled global source
      gload_lds16(A + (size_t)(brow + r) * K + kt + cl * 16, lA + t * 16 + i * 4096);
      gload_lds16(Bt + (size_t)(bcol + r) * K + kt + cl * 16, lB + t * 16 + i * 4096);
    }
    __syncthreads();
#pragma unroll
    for (int kk = 0; kk < BK / 32; ++kk) {
      int kb = kk * 32 + ((l >> 4) << 3);
      long av[4], bv[4];
#pragma unroll
      for (int mi = 0; mi < 4; ++mi) {
        int row = wm * 64 + mi * 16 + (l & 15);
        int off = row * BK + (((kb >> 4) ^ (row & 7)) << 4) + (kb & 15);
        av[mi] = *(const long*)(lA + off);
      }
#pragma unroll
      for (int ni = 0; ni < 4; ++ni) {
        int row = wn * 64 + ni * 16 + (l & 15);
        int off = row * BK + (((kb >> 4) ^ (row & 7)) << 4) + (kb & 15);
        bv[ni] = *(const long*)(lB + off);
      }
#pragma unroll
      for (int mi = 0; mi < 4; ++mi)
#pragma unroll
        for (int ni = 0; ni < 4; ++ni)
          acc[mi][ni] = __builtin_amdgcn_mfma_f32_16x16x32_fp8_fp8(
              av[mi], bv[ni], acc[mi][ni], 0, 0, 0);
    }
    __syncthreads();
  }

  float s1 = scales[0], s2 = scales[1];
  float factor = (1.0f / s1) * (1.0f / s2);
  int ccol = bcol + wn * 64 + (l & 15);
  int crow0 = brow + wm * 64 + ((l >> 4) << 2);
#pragma unroll
  for (int mi = 0; mi < 4; ++mi)
#pragma unroll
    for (int ni = 0; ni < 4; ++ni)
#pragma unroll
      for (int rr = 0; rr < 4; ++rr)
        C[(size_t)(crow0 + mi * 16 + rr) * N + ccol + ni * 16] =
            acc[mi][ni][rr] * factor;
}

// ---------------------------------------------------------------- launch --
extern "C" void kernel_launch(void* const* d_in, const int* in_sizes, int n_in,
                              void* d_out, int out_size, void* d_ws, size_t ws_size,
                              hipStream_t stream) {
  const float* in1 = (const float*)d_in[0];
  const float* in2 = (const float*)d_in[1];
  float* out = (float*)d_out;
  const int M = 4096, N = 4096, K = 4096;

  float* scales = (float*)d_ws;
  unsigned char* q1 = (unsigned char*)d_ws + 256;
  unsigned char* q2t = q1 + (size_t)M * K;
  float* partials = (float*)q1;   // overlay; dead before quant_fused writes q1

  const int blocksPer = 1024;
  amax_partial<<<2 * blocksPer, 256, 0, stream>>>(in1, in2, partials, (M * K) >> 2, blocksPer);
  amax_finalize<<<1, 256, 0, stream>>>(partials, scales, blocksPer);
  quant_fused<<<ABLK + 4096, 256, 0, stream>>>(in1, q1, in2, q2t, scales, (M * K) >> 2, N, K);
  gemm_fp8<<<dim3(N / BN, M / BM), 256, 0, stream>>>(q1, q2t, out, scales, M, N, K);
}